// Round 4
// baseline (1605.307 us; speedup 1.0000x reference)
//
#include <hip/hip_runtime.h>

// Problem constants (from reference)
#define NUM_F   26
#define DIM     128
#define NROWS   100000
#define BATCH   4096
#define TLEN    81920              // B * L indices per feature
#define CHUNKS_PER_F (TLEN / 64)   // 1280 64-index chunks per feature

// ---------------------------------------------------------------------------
// Prologue: zero the output (harness poisons d_out; main kernel uses a mix of
// plain stores and atomicAdd, so out must start at 0.0f).
// ---------------------------------------------------------------------------
__global__ __launch_bounds__(256) void zero_out_kernel(float4* __restrict__ out4, int n4)
{
    int i = blockIdx.x * blockDim.x + threadIdx.x;
    const int stride = gridDim.x * blockDim.x;
    const float4 z = {0.f, 0.f, 0.f, 0.f};
    for (; i < n4; i += stride) out4[i] = z;
}

// ---------------------------------------------------------------------------
// Main: one 64-lane wave per 64 consecutive index positions of one feature
// (equal work per wave — no bag-length imbalance).
//   1. coalesced load of 64 indices
//   2. per-lane binary search of offsets[f] (4097 ints, L1-resident) -> bag id
//   3. run-length segmented accumulation: lane i holds columns 2i, 2i+1;
//      each row is broadcast via readlane (SGPR base, coalesced 512B row load)
//   4. interior bags (start AND end inside this chunk): exclusive owner ->
//      plain float2 store. Chunk-boundary bags: atomicAdd onto zeroed out.
// ---------------------------------------------------------------------------
__global__ __launch_bounds__(256) void ebag_seg_kernel(
    const float* __restrict__ tables,   // [F, N, D] fp32
    const int*   __restrict__ values,   // [F, T] int32
    const int*   __restrict__ offsets,  // [F, B+1] int32
    float*       __restrict__ out)      // [B, F, D] fp32
{
    const int wid  = blockIdx.x * 4 + (threadIdx.x >> 6);   // global wave id
    const int lane = threadIdx.x & 63;

    const int f = wid / CHUNKS_PER_F;            // feature-major for L3 locality
    const int c = wid - f * CHUNKS_PER_F;
    const int cstart = c * 64;
    const int pos = cstart + lane;               // this lane's index position

    const int*   __restrict__ vals = values  + f * TLEN;
    const int*   __restrict__ offs = offsets + f * (BATCH + 1);
    const float* __restrict__ tab  = tables  + (size_t)f * NROWS * DIM;

    const int myidx = vals[pos];                 // coalesced [64] index load

    // Binary search: largest seg with offs[seg] <= pos.
    // Invariant: offs[lo] <= pos < offs[hi]; range 4096 = 2^12 -> 12 steps.
    int lo = 0, hi = BATCH;
    #pragma unroll
    for (int it = 0; it < 12; ++it) {
        const int m = (lo + hi) >> 1;
        if (offs[m] <= pos) lo = m; else hi = m;
    }
    const int myseg = lo;

    // Run-boundary mask: bit j set iff position j starts a new bag (bit 0 always).
    const int prev = __shfl_up(myseg, 1);
    const unsigned long long bmask = __ballot(myseg != prev) | 1ull;

    const unsigned colB = (unsigned)lane * 8u;   // byte offset of lane's float2 in a row
    float ax = 0.f, ay = 0.f;

    int j = 0;
    while (j < 64) {
        const unsigned long long rest = (j < 63) ? (bmask >> (j + 1)) : 0ull;
        const int next = rest ? (j + 1 + __builtin_ctzll(rest)) : 64;
        const int s = __builtin_amdgcn_readlane(myseg, j);

        // Accumulate rows j..next-1 of this bag (4-deep load pipeline).
        int k = j;
        for (; k + 4 <= next; k += 4) {
            const int i0 = __builtin_amdgcn_readlane(myidx, k + 0);
            const int i1 = __builtin_amdgcn_readlane(myidx, k + 1);
            const int i2 = __builtin_amdgcn_readlane(myidx, k + 2);
            const int i3 = __builtin_amdgcn_readlane(myidx, k + 3);
            const float2 v0 = *(const float2*)((const char*)tab + (((unsigned)i0 << 9) + colB));
            const float2 v1 = *(const float2*)((const char*)tab + (((unsigned)i1 << 9) + colB));
            const float2 v2 = *(const float2*)((const char*)tab + (((unsigned)i2 << 9) + colB));
            const float2 v3 = *(const float2*)((const char*)tab + (((unsigned)i3 << 9) + colB));
            ax += (v0.x + v1.x) + (v2.x + v3.x);
            ay += (v0.y + v1.y) + (v2.y + v3.y);
        }
        for (; k < next; ++k) {
            const int idx = __builtin_amdgcn_readlane(myidx, k);
            const float2 v = *(const float2*)((const char*)tab + (((unsigned)idx << 9) + colB));
            ax += v.x;
            ay += v.y;
        }

        // Flush bag s. First/last run of the chunk may be shared with the
        // neighboring chunk -> atomicAdd; interior runs are exclusively ours.
        float* ob = out + ((size_t)s * NUM_F + f) * DIM + (lane * 2);
        if (j == 0 || next == 64) {
            atomicAdd(ob + 0, ax);
            atomicAdd(ob + 1, ay);
        } else {
            float2 r; r.x = ax; r.y = ay;
            *(float2*)ob = r;
        }
        ax = 0.f; ay = 0.f;
        j = next;
    }
}

extern "C" void kernel_launch(void* const* d_in, const int* in_sizes, int n_in,
                              void* d_out, int out_size, void* d_ws, size_t ws_size,
                              hipStream_t stream) {
    const float* tables  = (const float*)d_in[0];
    const int*   values  = (const int*)d_in[1];
    const int*   offsets = (const int*)d_in[2];
    float*       out     = (float*)d_out;

    // 1) zero the (poisoned) output — required for the atomicAdd path.
    const int n4 = BATCH * NUM_F * DIM / 4;      // 3,407,872 float4s
    zero_out_kernel<<<dim3(1024), dim3(256), 0, stream>>>((float4*)out, n4);

    // 2) equal-work gather: 26 features x 1280 chunks = 33,280 waves.
    const int total_waves = NUM_F * CHUNKS_PER_F;
    const int blocks = total_waves / 4;          // 4 waves per 256-thread block
    ebag_seg_kernel<<<dim3(blocks), dim3(256), 0, stream>>>(tables, values, offsets, out);
}